// Round 9
// baseline (204.432 us; speedup 1.0000x reference)
//
#include <hip/hip_runtime.h>
#include <stdint.h>

#define NPTS 262144
#define NB 4
#define KSEL 4096
#define CAP 8192
#define CBLK 128                   // compact blocks per batch
#define HBLK 64                    // hist blocks per batch

// ---- workspace layout (bytes) ----
#define OFF_BITS  0ULL
#define OFF_H8P   (4ULL*NPTS*NB)                       // 4 MB (keys)
#define OFF_H12   (OFF_H8P + 4ULL*256*HBLK*NB)         // +256 KB (h8 partials)
#define OFF_CTRL  (OFF_H12 + 4ULL*4096*NB)             // +64 KB
#define OFF_CAND  (OFF_CTRL + 1024ULL)
#define WS_NEEDED (OFF_CAND + 8ULL*CAP*NB)             // +256 KB cand

// ---- output layout (float elements) ----
#define OBIN 0
#define ORES (NB*KSEL*5)           // 81920
#define OBOX (ORES + NB*KSEL)      // 98304
#define OCLS (OBOX + NB*KSEL*7)    // 212992

// ctrl per batch (16 u32): [0]=P8 [1]=count_above_P8 [2]=T20 [3]=cand_count

__device__ __forceinline__ uint32_t key_of(float mx) {
    uint32_t b = __float_as_uint(mx);
    uint32_t mask = ((int32_t)b >> 31) | 0x80000000u;
    return b ^ mask;
}

// ---------------- keys + per-block hi8 histogram partials (no atomics to global) ----
__global__ __launch_bounds__(256) void k_score_hist(
    const float* __restrict__ cls, uint32_t* __restrict__ bits, uint32_t* __restrict__ h8p)
{
    __shared__ uint32_t lh[8][256];
    for (int i = threadIdx.x; i < 2048; i += 256) ((uint32_t*)lh)[i] = 0;
    __syncthreads();
    int b = blockIdx.y;
    int sub = threadIdx.x >> 5;
    for (int it = 0; it < 4; ++it) {
        int chunk = blockIdx.x * 1024 + it * 256 + threadIdx.x;    // uint4-chunk in [0,65536)
        const float4* p = (const float4*)(cls + ((size_t)b * NPTS + (size_t)chunk * 4) * 3);
        float4 v0 = p[0], v1 = p[1], v2 = p[2];
        uint4 o;
        o.x = key_of(fmaxf(fmaxf(v0.x, v0.y), v0.z));
        o.y = key_of(fmaxf(fmaxf(v0.w, v1.x), v1.y));
        o.z = key_of(fmaxf(fmaxf(v1.z, v1.w), v2.x));
        o.w = key_of(fmaxf(fmaxf(v2.y, v2.z), v2.w));
        ((uint4*)(bits + (size_t)b * NPTS))[chunk] = o;
        atomicAdd(&lh[sub][o.x >> 24], 1u);
        atomicAdd(&lh[sub][o.y >> 24], 1u);
        atomicAdd(&lh[sub][o.z >> 24], 1u);
        atomicAdd(&lh[sub][o.w >> 24], 1u);
    }
    __syncthreads();
    uint32_t c = 0;
    #pragma unroll
    for (int s = 0; s < 8; ++s) c += lh[s][threadIdx.x];
    h8p[((size_t)b * HBLK + blockIdx.x) * 256 + threadIdx.x] = c;   // plain store
}

// ---------------- reduce partials, find P8; zero h12 + cand counter ----------------
__global__ __launch_bounds__(256) void k_scan8(
    const uint32_t* __restrict__ h8p, uint32_t* __restrict__ ctrl, uint32_t* __restrict__ h12)
{
    __shared__ uint32_t s[256];
    int b = blockIdx.x;
    uint32_t sum = 0;
    const uint32_t* base = h8p + (size_t)b * HBLK * 256 + threadIdx.x;
    #pragma unroll 8
    for (int blk = 0; blk < HBLK; ++blk) sum += base[blk * 256];
    s[threadIdx.x] = sum;
    // zero h12 for this batch (1024 uint4)
    uint4* z = (uint4*)(h12 + (size_t)b * 4096);
    #pragma unroll
    for (int i = 0; i < 4; ++i) z[threadIdx.x + i * 256] = make_uint4(0u, 0u, 0u, 0u);
    __syncthreads();
    if (threadIdx.x == 0) {
        ctrl[b * 16 + 3] = 0u;
        uint32_t running = 0;
        for (int i = 255; i >= 0; --i) {
            if (running + s[i] >= (uint32_t)KSEL) {
                ctrl[b * 16 + 0] = (uint32_t)i;      // P8
                ctrl[b * 16 + 1] = running;          // strictly above
                break;
            }
            running += s[i];
        }
    }
}

// ---------------- 12-bit histogram of the P8 bucket ----------------
__global__ __launch_bounds__(256) void k_hist12(
    const uint32_t* __restrict__ bits, const uint32_t* __restrict__ ctrl, uint32_t* __restrict__ h12)
{
    __shared__ uint32_t lh[4096];
    for (int i = threadIdx.x; i < 4096; i += 256) lh[i] = 0;
    __syncthreads();
    int b = blockIdx.y;
    uint32_t P8 = ctrl[b * 16 + 0];
    for (int it = 0; it < 4; ++it) {
        int chunk = blockIdx.x * 1024 + it * 256 + threadIdx.x;
        uint4 v = ((const uint4*)(bits + (size_t)b * NPTS))[chunk];
        if ((v.x >> 24) == P8) atomicAdd(&lh[(v.x >> 12) & 0xFFFu], 1u);
        if ((v.y >> 24) == P8) atomicAdd(&lh[(v.y >> 12) & 0xFFFu], 1u);
        if ((v.z >> 24) == P8) atomicAdd(&lh[(v.z >> 12) & 0xFFFu], 1u);
        if ((v.w >> 24) == P8) atomicAdd(&lh[(v.w >> 12) & 0xFFFu], 1u);
    }
    __syncthreads();
    for (int i = threadIdx.x; i < 4096; i += 256) {
        uint32_t c = lh[i];
        if (c) atomicAdd(&h12[(size_t)b * 4096 + i], c);
    }
}

// ---------------- find T20: bulk-load 4096 bins to LDS, scan ----------------
__global__ __launch_bounds__(256) void k_scan12(
    const uint32_t* __restrict__ h12, uint32_t* __restrict__ ctrl)
{
    __shared__ uint32_t bins[4096];
    __shared__ uint32_t part[256];
    int b = blockIdx.x;
    const uint4* src = (const uint4*)(h12 + (size_t)b * 4096);
    for (int i = threadIdx.x; i < 1024; i += 256)
        ((uint4*)bins)[i] = src[i];
    __syncthreads();
    uint32_t s = 0;
    int base = threadIdx.x * 16;
    #pragma unroll
    for (int j = 0; j < 16; ++j) s += bins[base + j];
    part[threadIdx.x] = s;
    __syncthreads();
    if (threadIdx.x == 0) {
        uint32_t K = (uint32_t)KSEL - ctrl[b * 16 + 1];
        uint32_t running = 0; int seg = 0;
        for (int t = 255; t >= 0; --t) {
            if (running + part[t] >= K) { seg = t; break; }
            running += part[t];
        }
        for (int i = 15; i >= 0; --i) {
            running += bins[seg * 16 + i];
            if (running >= K) {
                ctrl[b * 16 + 2] = (ctrl[b * 16 + 0] << 12) | (uint32_t)(seg * 16 + i);
                break;
            }
        }
    }
}

// ---------------- compact superset (key>>12 >= T20), block-aggregated atomic ----------------
__global__ __launch_bounds__(256) void k_compact(
    const uint32_t* __restrict__ bits, uint32_t* __restrict__ ctrl, uint64_t* __restrict__ cand)
{
    __shared__ uint32_t wbase[4];
    int b = blockIdx.y;
    uint32_t T = ctrl[b * 16 + 2];
    int lane = threadIdx.x & 63;
    int wave = threadIdx.x >> 6;
    uint64_t lmask = (1ull << lane) - 1ull;

    int chunk0 = blockIdx.x * 512 + threadIdx.x;
    const uint4* src = (const uint4*)(bits + (size_t)b * NPTS);
    uint4 v0 = src[chunk0];
    uint4 v1 = src[chunk0 + 256];
    uint32_t ks[8] = {v0.x, v0.y, v0.z, v0.w, v1.x, v1.y, v1.z, v1.w};
    bool sel[8];
    #pragma unroll
    for (int i = 0; i < 8; ++i) sel[i] = (ks[i] >> 12) >= T;

    uint32_t wsum = 0;
    #pragma unroll
    for (int i = 0; i < 8; ++i) wsum += (uint32_t)__popcll(__ballot(sel[i]));
    if (lane == 0) wbase[wave] = wsum;
    __syncthreads();
    if (threadIdx.x == 0) {
        uint32_t c0 = wbase[0], c1 = wbase[1], c2 = wbase[2], c3 = wbase[3];
        uint32_t tot = c0 + c1 + c2 + c3;
        uint32_t base = tot ? atomicAdd(&ctrl[b * 16 + 3], tot) : 0u;
        wbase[0] = base;
        wbase[1] = base + c0;
        wbase[2] = base + c0 + c1;
        wbase[3] = base + c0 + c1 + c2;
    }
    __syncthreads();
    uint32_t off = wbase[wave];
    #pragma unroll
    for (int i = 0; i < 8; ++i) {
        uint64_t m = __ballot(sel[i]);
        if (sel[i]) {
            uint32_t pos = off + (uint32_t)__popcll(m & lmask);
            uint32_t n = (uint32_t)(chunk0 + (i < 4 ? 0 : 256)) * 4 + (uint32_t)(i & 3);
            if (pos < CAP)
                cand[(size_t)b * CAP + pos] = ((uint64_t)(~ks[i]) << 32) | (uint64_t)n;
        }
        off += (uint32_t)__popcll(m);
    }
}

// ---------------- rank (scalar-load key stream, VALU compare) + gather ----------------
__global__ __launch_bounds__(256) void k_rankgather(
    const uint64_t* __restrict__ cand, const uint32_t* __restrict__ ctrl,
    const float* __restrict__ box, const float* __restrict__ cls, float* __restrict__ out)
{
    int b = blockIdx.y;
    uint32_t C = ctrl[b * 16 + 3];
    if (C > CAP) C = CAP;
    uint32_t item = blockIdx.x * 256 + threadIdx.x;
    if (blockIdx.x * 256 >= C) return;               // uniform early-exit
    const uint64_t* cb = cand + (size_t)b * CAP;     // cb[j] is wave-uniform -> s_load
    uint64_t me = (item < C) ? cb[item] : ~0ull;
    uint32_t r = 0;
    uint32_t j = 0;
    uint32_t C8 = C & ~7u;
    for (; j < C8; j += 8) {
        #pragma unroll
        for (int q = 0; q < 8; ++q) r += (cb[j + q] < me) ? 1u : 0u;
    }
    for (; j < C; ++j) r += (cb[j] < me) ? 1u : 0u;
    if (item < C && r < KSEL) {
        uint32_t n = (uint32_t)me;
        const float* bp = box + ((size_t)b * NPTS + n) * 7;
        float* ob = out + OBOX + ((size_t)b * KSEL + r) * 7;
        #pragma unroll
        for (int c = 0; c < 7; ++c) ob[c] = bp[c];
        const float* cp = cls + ((size_t)b * NPTS + n) * 3;
        float* oc = out + OCLS + ((size_t)b * KSEL + r) * 3;
        #pragma unroll
        for (int c = 0; c < 3; ++c) oc[c] = cp[c];
    }
}

// ---------------- fused conv1+bn+relu+conv2+bn+relu+heads ----------------
__global__ __launch_bounds__(256) void k_conv(
    const float* __restrict__ c1w, const float* __restrict__ g1v, const float* __restrict__ b1v,
    const float* __restrict__ m1v, const float* __restrict__ v1v,
    const float* __restrict__ c2w, const float* __restrict__ g2v, const float* __restrict__ b2v,
    const float* __restrict__ m2v, const float* __restrict__ v2v,
    const float* __restrict__ binw, const float* __restrict__ binb,
    const float* __restrict__ resw, const float* __restrict__ resb,
    float* __restrict__ out)
{
    __shared__ __align__(16) float w1s[960];       // [(i*3+tap)*32 + c]
    __shared__ __align__(16) float b1s[32];
    __shared__ __align__(16) float w2s[6144];      // [(i*3+tap)*64 + o]
    __shared__ __align__(16) float b2s[64];
    __shared__ __align__(16) float hws[6][64];     // bin0..4, res
    __shared__ __align__(16) float xin[10][80];
    __shared__ __align__(16) float x1s[32][68];
    __shared__ __align__(16) float x2t[64][68];

    int tid = threadIdx.x;
    int b = blockIdx.y;
    int tile0 = blockIdx.x * 64;
    const float* boxsel = out + OBOX + (size_t)b * KSEL * 7;
    const float* clssel = out + OCLS + (size_t)b * KSEL * 3;

    for (int t = tid; t < 960; t += 256) {
        int c = t / 30, r = t - c * 30, i = r / 3, tap = r - i * 3;
        float inv = g1v[c] * rsqrtf(v1v[c] + 1e-5f);
        w1s[(i * 3 + tap) * 32 + c] = c1w[t] * inv;
    }
    if (tid < 32) {
        float inv = g1v[tid] * rsqrtf(v1v[tid] + 1e-5f);
        b1s[tid] = b1v[tid] - m1v[tid] * inv;
    }
    for (int t = tid; t < 6144; t += 256) {
        int o = t / 96, r = t - o * 96, i = r / 3, tap = r - i * 3;
        float inv = g2v[o] * rsqrtf(v2v[o] + 1e-5f);
        w2s[(i * 3 + tap) * 64 + o] = c2w[t] * inv;
    }
    if (tid >= 64 && tid < 128) {
        int o = tid - 64;
        float inv = g2v[o] * rsqrtf(v2v[o] + 1e-5f);
        b2s[o] = b2v[o] - m2v[o] * inv;
    }
    for (int t = tid; t < 384; t += 256)
        ((float*)hws)[t] = (t < 320) ? binw[t] : resw[t - 320];

    for (int u = tid; u < 680; u += 256) {
        int c = u / 68, k2 = u - c * 68;
        int g = tile0 + k2 - 2;
        float val = 0.f;
        if (g >= 0 && g < KSEL) val = (c < 7) ? boxsel[g * 7 + c] : clssel[g * 3 + (c - 7)];
        xin[c][k2] = val;
    }
    __syncthreads();

    {
        int c = tid & 31, kg = tid >> 5;
        int k0 = kg * 9;
        int nk = 66 - k0; if (nk > 9) nk = 9;
        float a[9];
        #pragma unroll
        for (int kk = 0; kk < 9; ++kk) a[kk] = b1s[c];
        #pragma unroll 2
        for (int i = 0; i < 10; ++i) {
            float xv[11];
            #pragma unroll
            for (int j = 0; j < 11; ++j) xv[j] = xin[i][k0 + j];
            #pragma unroll
            for (int tap = 0; tap < 3; ++tap) {
                float w = w1s[(i * 3 + tap) * 32 + c];
                #pragma unroll
                for (int kk = 0; kk < 9; ++kk) a[kk] = fmaf(w, xv[kk + tap], a[kk]);
            }
        }
        for (int kk = 0; kk < nk; ++kk) {
            int k = k0 + kk, gp = tile0 + k - 1;
            x1s[c][k] = (gp >= 0 && gp < KSEL) ? fmaxf(a[kk], 0.f) : 0.f;
        }
    }
    __syncthreads();

    {
        int o = tid & 63, pg = tid >> 6;
        int p0 = pg * 16;
        float acc[16];
        float bz = b2s[o];
        #pragma unroll
        for (int kk = 0; kk < 16; ++kk) acc[kk] = bz;
        #pragma unroll 4
        for (int i = 0; i < 32; ++i) {
            float4 xq[5];
            const float4* xr = (const float4*)&x1s[i][p0];
            #pragma unroll
            for (int q = 0; q < 5; ++q) xq[q] = xr[q];
            const float* xf = (const float*)xq;
            float w0 = w2s[(i * 3 + 0) * 64 + o];
            float w1 = w2s[(i * 3 + 1) * 64 + o];
            float w2 = w2s[(i * 3 + 2) * 64 + o];
            #pragma unroll
            for (int kk = 0; kk < 16; ++kk) {
                float t0 = fmaf(w0, xf[kk], acc[kk]);
                t0 = fmaf(w1, xf[kk + 1], t0);
                acc[kk] = fmaf(w2, xf[kk + 2], t0);
            }
        }
        #pragma unroll
        for (int kk = 0; kk < 16; ++kk)
            x2t[p0 + kk][o] = fmaxf(acc[kk], 0.f);
    }
    __syncthreads();

    {
        int p = tid & 63, g = tid >> 6;
        const float4* xr = (const float4*)&x2t[p][0];
        const float4* hw4 = (const float4*)hws;
        size_t gpos = (size_t)b * KSEL + (size_t)(tile0 + p);
        if (g < 2) {
            int j0 = g * 2, j1 = j0 + 1;
            float s0 = 0.f, s1 = 0.f;
            #pragma unroll
            for (int q = 0; q < 16; ++q) {
                float4 xv = xr[q];
                float4 wa = hw4[j0 * 16 + q];
                float4 wb = hw4[j1 * 16 + q];
                s0 = fmaf(xv.x, wa.x, s0); s0 = fmaf(xv.y, wa.y, s0);
                s0 = fmaf(xv.z, wa.z, s0); s0 = fmaf(xv.w, wa.w, s0);
                s1 = fmaf(xv.x, wb.x, s1); s1 = fmaf(xv.y, wb.y, s1);
                s1 = fmaf(xv.z, wb.z, s1); s1 = fmaf(xv.w, wb.w, s1);
            }
            out[OBIN + gpos * 5 + j0] = s0 + binb[j0];
            out[OBIN + gpos * 5 + j1] = s1 + binb[j1];
        } else {
            int j = (g == 2) ? 4 : 5;
            float s = 0.f;
            #pragma unroll
            for (int q = 0; q < 16; ++q) {
                float4 xv = xr[q];
                float4 wa = hw4[j * 16 + q];
                s = fmaf(xv.x, wa.x, s); s = fmaf(xv.y, wa.y, s);
                s = fmaf(xv.z, wa.z, s); s = fmaf(xv.w, wa.w, s);
            }
            if (g == 2) out[OBIN + gpos * 5 + 4] = s + binb[4];
            else        out[ORES + gpos]         = s + resb[0];
        }
    }
}

extern "C" void kernel_launch(void* const* d_in, const int* in_sizes, int n_in,
                              void* d_out, int out_size, void* d_ws, size_t ws_size,
                              hipStream_t stream)
{
    const float* box  = (const float*)d_in[0];
    const float* cls  = (const float*)d_in[1];
    const float* c1w  = (const float*)d_in[2];
    const float* g1   = (const float*)d_in[3];
    const float* b1   = (const float*)d_in[4];
    const float* m1   = (const float*)d_in[5];
    const float* v1   = (const float*)d_in[6];
    const float* c2w  = (const float*)d_in[7];
    const float* g2   = (const float*)d_in[8];
    const float* b2   = (const float*)d_in[9];
    const float* m2   = (const float*)d_in[10];
    const float* v2   = (const float*)d_in[11];
    const float* binw = (const float*)d_in[12];
    const float* binb = (const float*)d_in[13];
    const float* resw = (const float*)d_in[14];
    const float* resb = (const float*)d_in[15];
    float* out = (float*)d_out;
    char* ws = (char*)d_ws;
    if (ws_size < WS_NEEDED) return;

    uint32_t* bits = (uint32_t*)(ws + OFF_BITS);
    uint32_t* h8p  = (uint32_t*)(ws + OFF_H8P);
    uint32_t* h12  = (uint32_t*)(ws + OFF_H12);
    uint32_t* ctrl = (uint32_t*)(ws + OFF_CTRL);
    uint64_t* cand = (uint64_t*)(ws + OFF_CAND);

    k_score_hist<<<dim3(HBLK, NB), 256, 0, stream>>>(cls, bits, h8p);
    k_scan8<<<NB, 256, 0, stream>>>(h8p, ctrl, h12);
    k_hist12<<<dim3(HBLK, NB), 256, 0, stream>>>(bits, ctrl, h12);
    k_scan12<<<NB, 256, 0, stream>>>(h12, ctrl);
    k_compact<<<dim3(CBLK, NB), 256, 0, stream>>>(bits, ctrl, cand);
    k_rankgather<<<dim3(CAP / 256, NB), 256, 0, stream>>>(cand, ctrl, box, cls, out);
    k_conv<<<dim3(64, NB), 256, 0, stream>>>(c1w, g1, b1, m1, v1, c2w, g2, b2, m2, v2,
                                             binw, binb, resw, resb, out);
}

// Round 10
// 83.639 us; speedup vs baseline: 2.4442x; 2.4442x over previous
//
#include <hip/hip_runtime.h>
#include <stdint.h>

#define NPTS 262144
#define NB 4
#define KSEL 4096
#define CAP 8192
#define SLICES 8
#define SLICE_LEN (CAP / SLICES)   // 1024 keys, 8 KB LDS
#define CBLK 128                   // compact blocks per batch
#define HBLK 64                    // hist blocks per batch

// ---- workspace layout (bytes) ----
#define OFF_BITS  0ULL
#define OFF_H8P   (4ULL*NPTS*NB)                       // 4 MB (keys)
#define OFF_H12   (OFF_H8P + 4ULL*256*HBLK*NB)         // +256 KB (h8 partials)
#define OFF_CTRL  (OFF_H12 + 4ULL*4096*NB)             // +64 KB
#define OFF_GRANK (OFF_CTRL + 1024ULL)
#define OFF_CAND  (OFF_GRANK + 4ULL*CAP*NB)            // +128 KB
#define WS_NEEDED (OFF_CAND + 8ULL*CAP*NB)             // +256 KB

// ---- output layout (float elements) ----
#define OBIN 0
#define ORES (NB*KSEL*5)           // 81920
#define OBOX (ORES + NB*KSEL)      // 98304
#define OCLS (OBOX + NB*KSEL*7)    // 212992

// ctrl per batch (16 u32): [0]=P8 [1]=count_above_P8 [2]=T20 [3]=cand_count

__device__ __forceinline__ uint32_t key_of(float mx) {
    uint32_t b = __float_as_uint(mx);
    uint32_t mask = ((int32_t)b >> 31) | 0x80000000u;
    return b ^ mask;
}

// ---------------- keys + per-block hi8 histogram partials (no global atomics) ----
__global__ __launch_bounds__(256) void k_score_hist(
    const float* __restrict__ cls, uint32_t* __restrict__ bits, uint32_t* __restrict__ h8p)
{
    __shared__ uint32_t lh[8][256];
    for (int i = threadIdx.x; i < 2048; i += 256) ((uint32_t*)lh)[i] = 0;
    __syncthreads();
    int b = blockIdx.y;
    int sub = threadIdx.x >> 5;
    for (int it = 0; it < 4; ++it) {
        int chunk = blockIdx.x * 1024 + it * 256 + threadIdx.x;    // uint4-chunk in [0,65536)
        const float4* p = (const float4*)(cls + ((size_t)b * NPTS + (size_t)chunk * 4) * 3);
        float4 v0 = p[0], v1 = p[1], v2 = p[2];
        uint4 o;
        o.x = key_of(fmaxf(fmaxf(v0.x, v0.y), v0.z));
        o.y = key_of(fmaxf(fmaxf(v0.w, v1.x), v1.y));
        o.z = key_of(fmaxf(fmaxf(v1.z, v1.w), v2.x));
        o.w = key_of(fmaxf(fmaxf(v2.y, v2.z), v2.w));
        ((uint4*)(bits + (size_t)b * NPTS))[chunk] = o;
        atomicAdd(&lh[sub][o.x >> 24], 1u);
        atomicAdd(&lh[sub][o.y >> 24], 1u);
        atomicAdd(&lh[sub][o.z >> 24], 1u);
        atomicAdd(&lh[sub][o.w >> 24], 1u);
    }
    __syncthreads();
    uint32_t c = 0;
    #pragma unroll
    for (int s = 0; s < 8; ++s) c += lh[s][threadIdx.x];
    h8p[((size_t)b * HBLK + blockIdx.x) * 256 + threadIdx.x] = c;   // plain store
}

// ---------------- reduce partials, find P8; zero h12 + grank + cand counter ----------------
__global__ __launch_bounds__(256) void k_scan8(
    const uint32_t* __restrict__ h8p, uint32_t* __restrict__ ctrl,
    uint32_t* __restrict__ h12, uint32_t* __restrict__ grank)
{
    __shared__ uint32_t s[256];
    int b = blockIdx.x;
    uint32_t sum = 0;
    const uint32_t* base = h8p + (size_t)b * HBLK * 256 + threadIdx.x;
    #pragma unroll 8
    for (int blk = 0; blk < HBLK; ++blk) sum += base[blk * 256];
    s[threadIdx.x] = sum;
    // zero h12 for this batch (1024 uint4)
    uint4* z = (uint4*)(h12 + (size_t)b * 4096);
    #pragma unroll
    for (int i = 0; i < 4; ++i) z[threadIdx.x + i * 256] = make_uint4(0u, 0u, 0u, 0u);
    // zero grank for this batch (2048 uint4)
    uint4* zg = (uint4*)(grank + (size_t)b * CAP);
    #pragma unroll
    for (int i = 0; i < 8; ++i) zg[threadIdx.x + i * 256] = make_uint4(0u, 0u, 0u, 0u);
    __syncthreads();
    if (threadIdx.x == 0) {
        ctrl[b * 16 + 3] = 0u;
        uint32_t running = 0;
        for (int i = 255; i >= 0; --i) {
            if (running + s[i] >= (uint32_t)KSEL) {
                ctrl[b * 16 + 0] = (uint32_t)i;      // P8
                ctrl[b * 16 + 1] = running;          // strictly above
                break;
            }
            running += s[i];
        }
    }
}

// ---------------- 12-bit histogram of the P8 bucket ----------------
__global__ __launch_bounds__(256) void k_hist12(
    const uint32_t* __restrict__ bits, const uint32_t* __restrict__ ctrl, uint32_t* __restrict__ h12)
{
    __shared__ uint32_t lh[4096];
    for (int i = threadIdx.x; i < 4096; i += 256) lh[i] = 0;
    __syncthreads();
    int b = blockIdx.y;
    uint32_t P8 = ctrl[b * 16 + 0];
    for (int it = 0; it < 4; ++it) {
        int chunk = blockIdx.x * 1024 + it * 256 + threadIdx.x;
        uint4 v = ((const uint4*)(bits + (size_t)b * NPTS))[chunk];
        if ((v.x >> 24) == P8) atomicAdd(&lh[(v.x >> 12) & 0xFFFu], 1u);
        if ((v.y >> 24) == P8) atomicAdd(&lh[(v.y >> 12) & 0xFFFu], 1u);
        if ((v.z >> 24) == P8) atomicAdd(&lh[(v.z >> 12) & 0xFFFu], 1u);
        if ((v.w >> 24) == P8) atomicAdd(&lh[(v.w >> 12) & 0xFFFu], 1u);
    }
    __syncthreads();
    for (int i = threadIdx.x; i < 4096; i += 256) {
        uint32_t c = lh[i];
        if (c) atomicAdd(&h12[(size_t)b * 4096 + i], c);
    }
}

// ---------------- find T20: bulk-load 4096 bins to LDS, scan ----------------
__global__ __launch_bounds__(256) void k_scan12(
    const uint32_t* __restrict__ h12, uint32_t* __restrict__ ctrl)
{
    __shared__ uint32_t bins[4096];
    __shared__ uint32_t part[256];
    int b = blockIdx.x;
    const uint4* src = (const uint4*)(h12 + (size_t)b * 4096);
    for (int i = threadIdx.x; i < 1024; i += 256)
        ((uint4*)bins)[i] = src[i];
    __syncthreads();
    uint32_t s = 0;
    int base = threadIdx.x * 16;
    #pragma unroll
    for (int j = 0; j < 16; ++j) s += bins[base + j];
    part[threadIdx.x] = s;
    __syncthreads();
    if (threadIdx.x == 0) {
        uint32_t K = (uint32_t)KSEL - ctrl[b * 16 + 1];
        uint32_t running = 0; int seg = 0;
        for (int t = 255; t >= 0; --t) {
            if (running + part[t] >= K) { seg = t; break; }
            running += part[t];
        }
        for (int i = 15; i >= 0; --i) {
            running += bins[seg * 16 + i];
            if (running >= K) {
                ctrl[b * 16 + 2] = (ctrl[b * 16 + 0] << 12) | (uint32_t)(seg * 16 + i);
                break;
            }
        }
    }
}

// ---------------- compact superset (key>>12 >= T20), block-aggregated atomic ----------------
__global__ __launch_bounds__(256) void k_compact(
    const uint32_t* __restrict__ bits, uint32_t* __restrict__ ctrl, uint64_t* __restrict__ cand)
{
    __shared__ uint32_t wbase[4];
    int b = blockIdx.y;
    uint32_t T = ctrl[b * 16 + 2];
    int lane = threadIdx.x & 63;
    int wave = threadIdx.x >> 6;
    uint64_t lmask = (1ull << lane) - 1ull;

    int chunk0 = blockIdx.x * 512 + threadIdx.x;
    const uint4* src = (const uint4*)(bits + (size_t)b * NPTS);
    uint4 v0 = src[chunk0];
    uint4 v1 = src[chunk0 + 256];
    uint32_t ks[8] = {v0.x, v0.y, v0.z, v0.w, v1.x, v1.y, v1.z, v1.w};
    bool sel[8];
    #pragma unroll
    for (int i = 0; i < 8; ++i) sel[i] = (ks[i] >> 12) >= T;

    uint32_t wsum = 0;
    #pragma unroll
    for (int i = 0; i < 8; ++i) wsum += (uint32_t)__popcll(__ballot(sel[i]));
    if (lane == 0) wbase[wave] = wsum;
    __syncthreads();
    if (threadIdx.x == 0) {
        uint32_t c0 = wbase[0], c1 = wbase[1], c2 = wbase[2], c3 = wbase[3];
        uint32_t tot = c0 + c1 + c2 + c3;
        uint32_t base = tot ? atomicAdd(&ctrl[b * 16 + 3], tot) : 0u;
        wbase[0] = base;
        wbase[1] = base + c0;
        wbase[2] = base + c0 + c1;
        wbase[3] = base + c0 + c1 + c2;
    }
    __syncthreads();
    uint32_t off = wbase[wave];
    #pragma unroll
    for (int i = 0; i < 8; ++i) {
        uint64_t m = __ballot(sel[i]);
        if (sel[i]) {
            uint32_t pos = off + (uint32_t)__popcll(m & lmask);
            uint32_t n = (uint32_t)(chunk0 + (i < 4 ? 0 : 256)) * 4 + (uint32_t)(i & 3);
            if (pos < CAP)
                cand[(size_t)b * CAP + pos] = ((uint64_t)(~ks[i]) << 32) | (uint64_t)n;
        }
        off += (uint32_t)__popcll(m);
    }
}

// ---------------- partial ranks over LDS key slices (broadcast reads) ----------------
__global__ __launch_bounds__(256) void k_rank1(
    const uint64_t* __restrict__ cand, const uint32_t* __restrict__ ctrl,
    uint32_t* __restrict__ grank)
{
    __shared__ uint64_t keys[SLICE_LEN];
    int b = blockIdx.z;
    uint32_t C = ctrl[b * 16 + 3];
    if (C > CAP) C = CAP;
    uint32_t k0 = blockIdx.y * SLICE_LEN;
    if (k0 >= C) return;
    uint32_t nk = C - k0; if (nk > SLICE_LEN) nk = SLICE_LEN;
    for (uint32_t i = threadIdx.x; i < nk; i += 256)
        keys[i] = cand[(size_t)b * CAP + k0 + i];
    __syncthreads();
    uint32_t item = blockIdx.x * 256 + threadIdx.x;
    if (item >= C) return;
    uint64_t me = cand[(size_t)b * CAP + item];
    uint32_t r = 0;
    #pragma unroll 16
    for (uint32_t i = 0; i < nk; ++i) r += (keys[i] < me) ? 1u : 0u;
    atomicAdd(&grank[b * CAP + item], r);
}

// ---------------- gather by rank ----------------
__global__ __launch_bounds__(256) void k_rank2(
    const uint64_t* __restrict__ cand, const uint32_t* __restrict__ ctrl,
    const uint32_t* __restrict__ grank,
    const float* __restrict__ box, const float* __restrict__ cls, float* __restrict__ out)
{
    int b = blockIdx.y;
    uint32_t C = ctrl[b * 16 + 3];
    if (C > CAP) C = CAP;
    uint32_t item = blockIdx.x * 256 + threadIdx.x;
    if (item >= C) return;
    uint64_t me = cand[(size_t)b * CAP + item];
    uint32_t rank = grank[b * CAP + item];
    if (rank < KSEL) {
        uint32_t n = (uint32_t)me;
        const float* bp = box + ((size_t)b * NPTS + n) * 7;
        float* ob = out + OBOX + ((size_t)b * KSEL + rank) * 7;
        #pragma unroll
        for (int c = 0; c < 7; ++c) ob[c] = bp[c];
        const float* cp = cls + ((size_t)b * NPTS + n) * 3;
        float* oc = out + OCLS + ((size_t)b * KSEL + rank) * 3;
        #pragma unroll
        for (int c = 0; c < 3; ++c) oc[c] = cp[c];
    }
}

// ---------------- fused conv1+bn+relu+conv2+bn+relu+heads ----------------
__global__ __launch_bounds__(256) void k_conv(
    const float* __restrict__ c1w, const float* __restrict__ g1v, const float* __restrict__ b1v,
    const float* __restrict__ m1v, const float* __restrict__ v1v,
    const float* __restrict__ c2w, const float* __restrict__ g2v, const float* __restrict__ b2v,
    const float* __restrict__ m2v, const float* __restrict__ v2v,
    const float* __restrict__ binw, const float* __restrict__ binb,
    const float* __restrict__ resw, const float* __restrict__ resb,
    float* __restrict__ out)
{
    __shared__ __align__(16) float w1s[960];       // [(i*3+tap)*32 + c]
    __shared__ __align__(16) float b1s[32];
    __shared__ __align__(16) float w2s[6144];      // [(i*3+tap)*64 + o]
    __shared__ __align__(16) float b2s[64];
    __shared__ __align__(16) float hws[6][64];     // bin0..4, res
    __shared__ __align__(16) float xin[10][80];
    __shared__ __align__(16) float x1s[32][68];
    __shared__ __align__(16) float x2t[64][68];

    int tid = threadIdx.x;
    int b = blockIdx.y;
    int tile0 = blockIdx.x * 64;
    const float* boxsel = out + OBOX + (size_t)b * KSEL * 7;
    const float* clssel = out + OCLS + (size_t)b * KSEL * 3;

    for (int t = tid; t < 960; t += 256) {
        int c = t / 30, r = t - c * 30, i = r / 3, tap = r - i * 3;
        float inv = g1v[c] * rsqrtf(v1v[c] + 1e-5f);
        w1s[(i * 3 + tap) * 32 + c] = c1w[t] * inv;
    }
    if (tid < 32) {
        float inv = g1v[tid] * rsqrtf(v1v[tid] + 1e-5f);
        b1s[tid] = b1v[tid] - m1v[tid] * inv;
    }
    for (int t = tid; t < 6144; t += 256) {
        int o = t / 96, r = t - o * 96, i = r / 3, tap = r - i * 3;
        float inv = g2v[o] * rsqrtf(v2v[o] + 1e-5f);
        w2s[(i * 3 + tap) * 64 + o] = c2w[t] * inv;
    }
    if (tid >= 64 && tid < 128) {
        int o = tid - 64;
        float inv = g2v[o] * rsqrtf(v2v[o] + 1e-5f);
        b2s[o] = b2v[o] - m2v[o] * inv;
    }
    for (int t = tid; t < 384; t += 256)
        ((float*)hws)[t] = (t < 320) ? binw[t] : resw[t - 320];

    for (int u = tid; u < 680; u += 256) {
        int c = u / 68, k2 = u - c * 68;
        int g = tile0 + k2 - 2;
        float val = 0.f;
        if (g >= 0 && g < KSEL) val = (c < 7) ? boxsel[g * 7 + c] : clssel[g * 3 + (c - 7)];
        xin[c][k2] = val;
    }
    __syncthreads();

    {
        int c = tid & 31, kg = tid >> 5;
        int k0 = kg * 9;
        int nk = 66 - k0; if (nk > 9) nk = 9;
        float a[9];
        #pragma unroll
        for (int kk = 0; kk < 9; ++kk) a[kk] = b1s[c];
        #pragma unroll 2
        for (int i = 0; i < 10; ++i) {
            float xv[11];
            #pragma unroll
            for (int j = 0; j < 11; ++j) xv[j] = xin[i][k0 + j];
            #pragma unroll
            for (int tap = 0; tap < 3; ++tap) {
                float w = w1s[(i * 3 + tap) * 32 + c];
                #pragma unroll
                for (int kk = 0; kk < 9; ++kk) a[kk] = fmaf(w, xv[kk + tap], a[kk]);
            }
        }
        for (int kk = 0; kk < nk; ++kk) {
            int k = k0 + kk, gp = tile0 + k - 1;
            x1s[c][k] = (gp >= 0 && gp < KSEL) ? fmaxf(a[kk], 0.f) : 0.f;
        }
    }
    __syncthreads();

    {
        int o = tid & 63, pg = tid >> 6;
        int p0 = pg * 16;
        float acc[16];
        float bz = b2s[o];
        #pragma unroll
        for (int kk = 0; kk < 16; ++kk) acc[kk] = bz;
        #pragma unroll 4
        for (int i = 0; i < 32; ++i) {
            float4 xq[5];
            const float4* xr = (const float4*)&x1s[i][p0];
            #pragma unroll
            for (int q = 0; q < 5; ++q) xq[q] = xr[q];
            const float* xf = (const float*)xq;
            float w0 = w2s[(i * 3 + 0) * 64 + o];
            float w1 = w2s[(i * 3 + 1) * 64 + o];
            float w2 = w2s[(i * 3 + 2) * 64 + o];
            #pragma unroll
            for (int kk = 0; kk < 16; ++kk) {
                float t0 = fmaf(w0, xf[kk], acc[kk]);
                t0 = fmaf(w1, xf[kk + 1], t0);
                acc[kk] = fmaf(w2, xf[kk + 2], t0);
            }
        }
        #pragma unroll
        for (int kk = 0; kk < 16; ++kk)
            x2t[p0 + kk][o] = fmaxf(acc[kk], 0.f);
    }
    __syncthreads();

    {
        int p = tid & 63, g = tid >> 6;
        const float4* xr = (const float4*)&x2t[p][0];
        const float4* hw4 = (const float4*)hws;
        size_t gpos = (size_t)b * KSEL + (size_t)(tile0 + p);
        if (g < 2) {
            int j0 = g * 2, j1 = j0 + 1;
            float s0 = 0.f, s1 = 0.f;
            #pragma unroll
            for (int q = 0; q < 16; ++q) {
                float4 xv = xr[q];
                float4 wa = hw4[j0 * 16 + q];
                float4 wb = hw4[j1 * 16 + q];
                s0 = fmaf(xv.x, wa.x, s0); s0 = fmaf(xv.y, wa.y, s0);
                s0 = fmaf(xv.z, wa.z, s0); s0 = fmaf(xv.w, wa.w, s0);
                s1 = fmaf(xv.x, wb.x, s1); s1 = fmaf(xv.y, wb.y, s1);
                s1 = fmaf(xv.z, wb.z, s1); s1 = fmaf(xv.w, wb.w, s1);
            }
            out[OBIN + gpos * 5 + j0] = s0 + binb[j0];
            out[OBIN + gpos * 5 + j1] = s1 + binb[j1];
        } else {
            int j = (g == 2) ? 4 : 5;
            float s = 0.f;
            #pragma unroll
            for (int q = 0; q < 16; ++q) {
                float4 xv = xr[q];
                float4 wa = hw4[j * 16 + q];
                s = fmaf(xv.x, wa.x, s); s = fmaf(xv.y, wa.y, s);
                s = fmaf(xv.z, wa.z, s); s = fmaf(xv.w, wa.w, s);
            }
            if (g == 2) out[OBIN + gpos * 5 + 4] = s + binb[4];
            else        out[ORES + gpos]         = s + resb[0];
        }
    }
}

extern "C" void kernel_launch(void* const* d_in, const int* in_sizes, int n_in,
                              void* d_out, int out_size, void* d_ws, size_t ws_size,
                              hipStream_t stream)
{
    const float* box  = (const float*)d_in[0];
    const float* cls  = (const float*)d_in[1];
    const float* c1w  = (const float*)d_in[2];
    const float* g1   = (const float*)d_in[3];
    const float* b1   = (const float*)d_in[4];
    const float* m1   = (const float*)d_in[5];
    const float* v1   = (const float*)d_in[6];
    const float* c2w  = (const float*)d_in[7];
    const float* g2   = (const float*)d_in[8];
    const float* b2   = (const float*)d_in[9];
    const float* m2   = (const float*)d_in[10];
    const float* v2   = (const float*)d_in[11];
    const float* binw = (const float*)d_in[12];
    const float* binb = (const float*)d_in[13];
    const float* resw = (const float*)d_in[14];
    const float* resb = (const float*)d_in[15];
    float* out = (float*)d_out;
    char* ws = (char*)d_ws;
    if (ws_size < WS_NEEDED) return;

    uint32_t* bits  = (uint32_t*)(ws + OFF_BITS);
    uint32_t* h8p   = (uint32_t*)(ws + OFF_H8P);
    uint32_t* h12   = (uint32_t*)(ws + OFF_H12);
    uint32_t* ctrl  = (uint32_t*)(ws + OFF_CTRL);
    uint32_t* grank = (uint32_t*)(ws + OFF_GRANK);
    uint64_t* cand  = (uint64_t*)(ws + OFF_CAND);

    k_score_hist<<<dim3(HBLK, NB), 256, 0, stream>>>(cls, bits, h8p);
    k_scan8<<<NB, 256, 0, stream>>>(h8p, ctrl, h12, grank);
    k_hist12<<<dim3(HBLK, NB), 256, 0, stream>>>(bits, ctrl, h12);
    k_scan12<<<NB, 256, 0, stream>>>(h12, ctrl);
    k_compact<<<dim3(CBLK, NB), 256, 0, stream>>>(bits, ctrl, cand);
    k_rank1<<<dim3(CAP / 256, SLICES, NB), 256, 0, stream>>>(cand, ctrl, grank);
    k_rank2<<<dim3(CAP / 256, NB), 256, 0, stream>>>(cand, ctrl, grank, box, cls, out);
    k_conv<<<dim3(64, NB), 256, 0, stream>>>(c1w, g1, b1, m1, v1, c2w, g2, b2, m2, v2,
                                             binw, binb, resw, resb, out);
}